// Round 9
// baseline (134.083 us; speedup 1.0000x reference)
//
#include <hip/hip_runtime.h>

// NCE loss: out0 = align + w*uniform, out1 = align, out2 = uniform
// align[n]   = logsig(ref[n]·pos[n]/T)
// uniform[n] = mean_m logsig(-ref[n]·neg[m]/T)
// N=M=8192, D=512, T=0.5, w=1.0
//
// Round 9: persistent blocks. grid=256 (1 block/CU); each block keeps one
// 256-row A band and walks 4 B column-tiles; 8-phase counted-vmcnt pipeline
// runs seamlessly across tile boundaries (32 K-tiles, one prologue/drain per
// block). Per-tile epilogue split into 2 chunks injected into ph1/ph3 of the
// next tile's first K-tile. Phase order (m0n0,m0n1,m1n0,m1n1); stage order
// A-h0,B-h0,B-h1,A-h1; uniform vmcnt(4) ledger (FIFO-verified).

typedef __attribute__((ext_vector_type(8))) short short8;
typedef __attribute__((ext_vector_type(8))) unsigned short ushort8;
typedef __attribute__((ext_vector_type(4))) float f32x4;

constexpr int N_ = 8192;
constexpr int M_ = 8192;
constexpr int D_ = 512;
constexpr float INV_T = 2.0f;
constexpr float NEG_W = 1.0f;
constexpr float LOG2E = 1.4426950408889634f;
constexpr float LN2   = 0.6931471805599453f;

__device__ __forceinline__ unsigned short f2bf(float f) {
  unsigned int u = __builtin_bit_cast(unsigned int, f);
  u += 0x7FFFu + ((u >> 16) & 1u);  // RNE
  return (unsigned short)(u >> 16);
}

__device__ __forceinline__ float logsig_neg(float s) {
  // log sigmoid(-s) = min(-s,0) - log1p(exp(-|s|))
  float t = __builtin_fabsf(s);
  float e = __builtin_amdgcn_exp2f(-t * LOG2E);
  float l = __builtin_amdgcn_logf(1.0f + e) * LN2;
  return fminf(-s, 0.0f) - l;
}

// fp32 -> bf16 with intra-row 16B-chunk XOR involution pre-applied
// (chunk c stored at c ^ (row&7) within each 128B K-segment) so linear
// global_load_lds staging yields the swizzled LDS layout (rule #21).
__global__ __launch_bounds__(256) void cvt_pack(
    const float* __restrict__ refp, const float* __restrict__ negp,
    unsigned short* __restrict__ abf, unsigned short* __restrict__ bbf) {
  const int b = blockIdx.x;
  const float* src = (b < 2048) ? refp : negp;
  unsigned short* dst = (b < 2048) ? abf : bbf;
  const int i = (b & 2047) * 256 + threadIdx.x;  // 16B-chunk index
  const f32x4* s = reinterpret_cast<const f32x4*>(src) + (size_t)i * 2;
  f32x4 v0 = s[0], v1 = s[1];
  ushort8 o;
#pragma unroll
  for (int j = 0; j < 4; ++j) {
    o[j]     = f2bf(v0[j]);
    o[4 + j] = f2bf(v1[j]);
  }
  const unsigned int row = (unsigned int)i >> 6;
  const unsigned int seg = ((unsigned int)i >> 3) & 7;
  const unsigned int c   = (unsigned int)i & 7;
  const size_t byte =
      (size_t)row * 1024 + seg * 128 + (size_t)((c ^ (row & 7u)) << 4);
  *reinterpret_cast<ushort8*>(reinterpret_cast<char*>(dst) + byte) = o;
}

__global__ __launch_bounds__(512, 2) void nce_gemm(
    const unsigned short* __restrict__ A,  // ref bf16, pre-swizzled rows
    const unsigned short* __restrict__ B,  // neg bf16, pre-swizzled rows
    float* __restrict__ rowsum) {          // (N,) fp32, pre-zeroed
  extern __shared__ char lds[];
  char* As = lds;           // 2 bufs x 256 rows x 128 B
  char* Bs = lds + 65536;   // 2 bufs x 256 rows x 128 B

  const int tid  = threadIdx.x;
  const int lane = tid & 63;
  const int wid  = tid >> 6;   // 0..7
  const int wr   = wid >> 2;   // 0..1 (A half: 128 rows)
  const int wc   = wid & 3;    // 0..3 (B quarter: 64 cols)

  // persistent mapping: 256 blocks = 8 XCD x 4 bands x 8 colgroups;
  // block walks 4 B tiles (colgrp*4 + tau), keeping its A band.
  const int cu     = blockIdx.x;   // 0..255
  const int x      = cu & 7;       // XCD
  const int q      = cu >> 3;      // 0..31
  const int band   = q & 3;
  const int colgrp = q >> 2;       // 0..7
  const int brow   = (x * 4 + band) * 256;

  // staging lane address (global stored layout == desired LDS layout)
  const size_t laneoff = (size_t)(lane >> 3) * 1024 + (size_t)(lane & 7) * 16;
  const char* gA  = reinterpret_cast<const char*>(A) + (size_t)brow * 1024 + laneoff;
  const char* gB0 = reinterpret_cast<const char*>(B) +
                    (size_t)colgrp * 4 * 262144 + laneoff;

  // fragment-read constants (proven conflict-free 16-lane pattern)
  const int r  = lane & 15;
  const int g4 = lane >> 4;
  const int c0 = ((g4 ^ (r & 7)) << 4);
  const int c1 = (((4 + g4) ^ (r & 7)) << 4);

  f32x4 acc[8][4] = {};
  short8 aLo[4][2], aHi[4][2], bv0[2][2], bv1[2][2];

  // ---- stage one half-tile (16 KiB), 2 glds per thread ----
#define STAGE_A(kof, buf, h)                                                  \
  {                                                                           \
    _Pragma("unroll") for (int j = 0; j < 2; ++j) {                           \
      const int u  = wid * 2 + j;                                             \
      const int rb = (u >> 3) * 128 + (u & 7) * 8 + (h) * 64;                 \
      __builtin_amdgcn_global_load_lds(                                       \
          (const __attribute__((address_space(1))) unsigned int*)(            \
              gA + (size_t)rb * 1024 + (kof)),                                \
          (__attribute__((address_space(3))) unsigned int*)(                  \
              As + (buf) * 32768 + rb * 128),                                 \
          16, 0, 0);                                                          \
    }                                                                         \
  }
#define STAGE_B(kof, buf, h, BB)                                              \
  {                                                                           \
    _Pragma("unroll") for (int j = 0; j < 2; ++j) {                           \
      const int u  = wid * 2 + j;                                             \
      const int rb = (u >> 2) * 64 + (u & 3) * 8 + (h) * 32;                  \
      __builtin_amdgcn_global_load_lds(                                       \
          (const __attribute__((address_space(1))) unsigned int*)(            \
              (BB) + (size_t)rb * 1024 + (kof)),                              \
          (__attribute__((address_space(3))) unsigned int*)(                  \
              Bs + (buf) * 32768 + rb * 128),                                 \
          16, 0, 0);                                                          \
    }                                                                         \
  }

#define READ_A(buf, mp, DST)                                                  \
  {                                                                           \
    _Pragma("unroll") for (int mf = 0; mf < 4; ++mf) {                        \
      const int ro = (wr * 128 + (mp)*64 + mf * 16 + r) * 128;                \
      DST[mf][0] =                                                            \
          *reinterpret_cast<const short8*>(As + (buf)*32768 + ro + c0);       \
      DST[mf][1] =                                                            \
          *reinterpret_cast<const short8*>(As + (buf)*32768 + ro + c1);       \
    }                                                                         \
  }
#define READ_B(buf, nh, DST)                                                  \
  {                                                                           \
    _Pragma("unroll") for (int nf = 0; nf < 2; ++nf) {                        \
      const int ro = (wc * 64 + (nh)*32 + nf * 16 + r) * 128;                 \
      DST[nf][0] =                                                            \
          *reinterpret_cast<const short8*>(Bs + (buf)*32768 + ro + c0);       \
      DST[nf][1] =                                                            \
          *reinterpret_cast<const short8*>(Bs + (buf)*32768 + ro + c1);       \
    }                                                                         \
  }

#define WAITBAR()                                                             \
  asm volatile("s_waitcnt vmcnt(4)\n\ts_barrier" ::: "memory")
#define NOWAITBAR() asm volatile("s_barrier" ::: "memory")

#define CLUSTER(mp, nh, AV, BV)                                               \
  {                                                                           \
    __builtin_amdgcn_s_setprio(1);                                            \
    _Pragma("unroll") for (int k = 0; k < 2; ++k)                             \
    _Pragma("unroll") for (int mf = 0; mf < 4; ++mf)                          \
    _Pragma("unroll") for (int nf = 0; nf < 2; ++nf)                          \
      acc[(mp)*4 + mf][(nh)*2 + nf] = __builtin_amdgcn_mfma_f32_16x16x32_bf16(\
          AV[mf][k], BV[nf][k], acc[(mp)*4 + mf][(nh)*2 + nf], 0, 0, 0);      \
    __builtin_amdgcn_s_setprio(0);                                            \
  }

  // full-row epilogue chunk for A-half mp: logsig over all 4 n-frags,
  // 16-lane shfl reduce, one atomic per row, zero acc half.
#define EPIF(mp)                                                              \
  {                                                                           \
    _Pragma("unroll") for (int mf = 0; mf < 4; ++mf) {                        \
      float s4[4];                                                            \
      _Pragma("unroll") for (int rr = 0; rr < 4; ++rr) {                      \
        float ss = 0.0f;                                                      \
        _Pragma("unroll") for (int an = 0; an < 4; ++an)                      \
            ss += logsig_neg(acc[(mp)*4 + mf][an][rr] * INV_T);               \
        ss += __shfl_xor(ss, 1);                                              \
        ss += __shfl_xor(ss, 2);                                              \
        ss += __shfl_xor(ss, 4);                                              \
        ss += __shfl_xor(ss, 8);                                              \
        s4[rr] = ss;                                                          \
      }                                                                       \
      if ((lane & 15) == 0) {                                                 \
        _Pragma("unroll") for (int rr = 0; rr < 4; ++rr)                      \
            atomicAdd(&rowsum[brow + wr * 128 + ((mp)*4 + mf) * 16 +          \
                              (lane >> 4) * 4 + rr],                          \
                      s4[rr]);                                                \
      }                                                                       \
      _Pragma("unroll") for (int an = 0; an < 4; ++an)                        \
          acc[(mp)*4 + mf][an] = (f32x4)0.0f;                                 \
    }                                                                         \
  }

  // ---- prologue: tile tau=0, K-tile 0 into buf0; order A0,B0,B1,A1 ----
  STAGE_A(0, 0, 0);
  STAGE_B(0, 0, 0, gB0);
  STAGE_B(0, 0, 1, gB0);
  STAGE_A(0, 0, 1);
  WAITBAR();  // retires A(0,h0),B(0,h0); queue = [B(0,h1), A(0,h1)]

  // ---- persistent walk: 4 tiles x 4 pairs x 8 phases ----
#pragma unroll 1
  for (int tau = 0; tau < 4; ++tau) {
    const char* Bc = gB0 + (size_t)tau * 262144;
    const char* Bn = gB0 + (size_t)(tau < 3 ? tau + 1 : 3) * 262144;
#pragma unroll
    for (int pp = 0; pp < 4; ++pp) {
      const int e  = 2 * pp;             // local K-tiles e (buf0), e+1 (buf1)
      const int k1 = ((e + 1) & 7) * 128;
      const int k2 = ((e + 2) & 7) * 128;
      const char* B2 = (pp == 3) ? Bn : Bc;  // K-tile e+2 crosses at pp=3
      const bool epi = (pp == 0) && (tau > 0);

      // ph1: (m0,n0) buf0
      READ_A(0, 0, aLo);
      READ_B(0, 0, bv0);
      STAGE_A(k1, 1, 0);
      WAITBAR();          // retires B(e,h1) -> ph2 read
      if (epi) EPIF(0);
      CLUSTER(0, 0, aLo, bv0);
      // ph2: (m0,n1)
      READ_B(0, 1, bv1);
      STAGE_B(k1, 1, 0, Bc);
      WAITBAR();          // retires A(e,h1) -> ph3 read
      CLUSTER(0, 1, aLo, bv1);
      // ph3: (m1,n0)
      READ_A(0, 1, aHi);
      STAGE_B(k1, 1, 1, Bc);
      NOWAITBAR();
      if (epi) EPIF(1);
      CLUSTER(1, 0, aHi, bv0);
      // ph4: (m1,n1)
      STAGE_A(k1, 1, 1);
      WAITBAR();          // retires A(e+1,h0),B(e+1,h0) -> ph5 reads
      CLUSTER(1, 1, aHi, bv1);
      // ph5: (m0,n0) buf1
      READ_A(1, 0, aLo);
      READ_B(1, 0, bv0);
      STAGE_A(k2, 0, 0);
      WAITBAR();          // retires B(e+1,h1) -> ph6 read
      CLUSTER(0, 0, aLo, bv0);
      // ph6: (m0,n1)
      READ_B(1, 1, bv1);
      STAGE_B(k2, 0, 0, B2);
      WAITBAR();          // retires A(e+1,h1) -> ph7 read
      CLUSTER(0, 1, aLo, bv1);
      // ph7: (m1,n0)
      READ_A(1, 1, aHi);
      STAGE_B(k2, 0, 1, B2);
      NOWAITBAR();
      CLUSTER(1, 0, aHi, bv0);
      // ph8: (m1,n1)
      STAGE_A(k2, 0, 1);
      WAITBAR();          // retires A(e+2,h0),B(e+2,h0) -> next ph1 reads
      CLUSTER(1, 1, aHi, bv1);
    }
  }
  asm volatile("s_waitcnt vmcnt(0)" ::: "memory");  // retire tail stages
#undef STAGE_A
#undef STAGE_B
#undef READ_A
#undef READ_B
#undef CLUSTER

  // ---- final epilogue: tile tau=3 ----
  EPIF(0);
  EPIF(1);
#undef EPIF
}

__global__ __launch_bounds__(256) void nce_combine(
    const float* __restrict__ ref, const float* __restrict__ pos,
    const float* __restrict__ rowsum, float* __restrict__ out) {
  const int wid  = threadIdx.x >> 6;
  const int lane = threadIdx.x & 63;
  const int n    = blockIdx.x * 4 + wid;

  const f32x4* pr =
      reinterpret_cast<const f32x4*>(ref + (size_t)n * D_ + lane * 8);
  const f32x4* pp =
      reinterpret_cast<const f32x4*>(pos + (size_t)n * D_ + lane * 8);
  f32x4 a0 = pr[0], a1 = pr[1], b0 = pp[0], b1 = pp[1];
  float d = 0.0f;
#pragma unroll
  for (int i = 0; i < 4; ++i) d = __builtin_fmaf(a0[i], b0[i], d);
#pragma unroll
  for (int i = 0; i < 4; ++i) d = __builtin_fmaf(a1[i], b1[i], d);
#pragma unroll
  for (int s = 1; s < 64; s <<= 1) d += __shfl_xor(d, s);

  if (lane == 0) {
    float z = d * INV_T;
    float align   = logsig_neg(-z);
    float uniform = rowsum[n] * (1.0f / (float)M_);
    out[n]          = align + NEG_W * uniform;
    out[N_ + n]     = align;
    out[2 * N_ + n] = uniform;
  }
}

extern "C" void kernel_launch(void* const* d_in, const int* in_sizes, int n_in,
                              void* d_out, int out_size, void* d_ws,
                              size_t ws_size, hipStream_t stream) {
  const float* ref = (const float*)d_in[0];
  const float* pos = (const float*)d_in[1];
  const float* neg = (const float*)d_in[2];
  float* out = (float*)d_out;

  float* rowsum = (float*)d_ws;                                  // 32 KB
  unsigned short* abf = (unsigned short*)((char*)d_ws + 32768);  // 8 MB
  unsigned short* bbf = abf + (size_t)N_ * D_;                   // 8 MB

  (void)hipFuncSetAttribute((const void*)nce_gemm,
                            hipFuncAttributeMaxDynamicSharedMemorySize,
                            131072);

  hipMemsetAsync(rowsum, 0, N_ * sizeof(float), stream);
  cvt_pack<<<4096, 256, 0, stream>>>(ref, neg, abf, bbf);
  nce_gemm<<<256, 512, 131072, stream>>>(abf, bbf, rowsum);
  nce_combine<<<N_ / 4, 256, 0, stream>>>(ref, pos, rowsum, out);
}

// Round 10
// 90.972 us; speedup vs baseline: 1.4739x; 1.4739x over previous
//
#include <hip/hip_runtime.h>
#include <hip/hip_fp8.h>

// NCE loss: out0 = align + w*uniform, out1 = align, out2 = uniform
// align[n]   = logsig(ref[n]·pos[n]/T)
// uniform[n] = mean_m logsig(-ref[n]·neg[m]/T)
// N=M=8192, D=512, T=0.5, w=1.0
//
// Round 10: round-8 structure (best: 93us) with MX-scaled fp8 (e4m3,
// scale=1.0) 16x16x128 MFMA — 2x matrix rate, half LDS/stage bytes.
// 256x256 tile, 8 waves, 4 K-tiles of 128, 16 phases, single barrier
// per phase, counted vmcnt(4), setprio, proven chunk^(row&7) swizzle.

typedef __attribute__((ext_vector_type(4)))  float f32x4;
typedef __attribute__((ext_vector_type(4)))  int   int4v;
typedef __attribute__((ext_vector_type(8)))  int   int8v;
typedef __attribute__((ext_vector_type(16))) unsigned char uchar16;

constexpr int N_ = 8192;
constexpr int M_ = 8192;
constexpr int D_ = 512;
constexpr float INV_T = 2.0f;
constexpr float NEG_W = 1.0f;
constexpr float LOG2E = 1.4426950408889634f;
constexpr float LN2   = 0.6931471805599453f;
constexpr unsigned SCALE1 = 0x7F7F7F7Fu;  // E8M0 = 127 -> 2^0 = 1.0

__device__ __forceinline__ float logsig_neg(float s) {
  // log sigmoid(-s) = min(-s,0) - log1p(exp(-|s|))
  float t = __builtin_fabsf(s);
  float e = __builtin_amdgcn_exp2f(-t * LOG2E);
  float l = __builtin_amdgcn_logf(1.0f + e) * LN2;
  return fminf(-s, 0.0f) - l;
}

// fp32 -> fp8 e4m3 (OCP), with the intra-row 16B-chunk XOR involution
// pre-applied: row = 512B = 4 K-segments x 128B; chunk c of a segment is
// stored at c ^ (row&7). Linear global_load_lds staging then yields the
// swizzled LDS layout (rule #21) read back by the fragment loads.
__global__ __launch_bounds__(256) void cvt_pack(
    const float* __restrict__ refp, const float* __restrict__ negp,
    unsigned char* __restrict__ a8, unsigned char* __restrict__ b8) {
  const int b = blockIdx.x;
  const float* src = (b < 1024) ? refp : negp;
  unsigned char* dst = (b < 1024) ? a8 : b8;
  const int i = (b & 1023) * 256 + threadIdx.x;  // 16B-chunk index
  const float* s = src + (size_t)i * 16;
  uchar16 o;
#pragma unroll
  for (int j = 0; j < 16; ++j) {
    __hip_fp8_e4m3 q(s[j]);
    o[j] = q.__x;
  }
  const unsigned int row = (unsigned int)i >> 5;  // 32 chunks per 512-el row
  const unsigned int seg = ((unsigned int)i >> 3) & 3;  // 128B K-segment
  const unsigned int c   = (unsigned int)i & 7;         // chunk in segment
  const size_t byte =
      (size_t)row * 512 + seg * 128 + (size_t)((c ^ (row & 7u)) << 4);
  *reinterpret_cast<uchar16*>(dst + byte) = o;
}

__global__ __launch_bounds__(512, 2) void nce_gemm(
    const unsigned char* __restrict__ A,  // ref fp8, pre-swizzled rows
    const unsigned char* __restrict__ B,  // neg fp8, pre-swizzled rows
    float* __restrict__ rowsum) {         // (N,) fp32, pre-zeroed
  extern __shared__ char lds[];
  char* As = lds;           // 2 bufs x 256 rows x 128 B
  char* Bs = lds + 65536;   // 2 bufs x 256 rows x 128 B

  const int tid  = threadIdx.x;
  const int lane = tid & 63;
  const int wid  = tid >> 6;   // 0..7
  const int wr   = wid >> 2;   // 0..1 (A half: 128 rows)
  const int wc   = wid & 3;    // 0..3 (B quarter: 64 cols)

  // XCD band swizzle: 1024 blocks, 8 XCDs, 4 row-bands/XCD, col-major in band
  const int bid  = blockIdx.x;
  const int x    = bid & 7;
  const int t    = bid >> 3;  // 0..127
  const int brow = (x * 4 + (t & 3)) * 256;
  const int bcol = (t >> 2) * 256;

  // staging lane address (global stored layout == desired LDS layout)
  const size_t laneoff = (size_t)(lane >> 3) * 512 + (size_t)(lane & 7) * 16;
  const char* gA = reinterpret_cast<const char*>(A) + (size_t)brow * 512 + laneoff;
  const char* gB = reinterpret_cast<const char*>(B) + (size_t)bcol * 512 + laneoff;

  // fragment-read constants: lane holds row (lane&15), K-bytes
  // [(lane>>4)*32, +32) = stored chunks (2g4, 2g4+1) ^ (row&7)
  const int r  = lane & 15;
  const int g4 = lane >> 4;
  const int c0 = (((2 * g4) ^ (r & 7)) << 4);
  const int c1 = (((2 * g4 + 1) ^ (r & 7)) << 4);

  f32x4 acc[8][4] = {};
  int8v aLo[4], aHi[4], bv0[2], bv1[2];

  // ---- stage one half-tile (16 KiB), 2 glds per thread ----
#define STAGE_A(g, h)                                                         \
  {                                                                           \
    _Pragma("unroll") for (int j = 0; j < 2; ++j) {                           \
      const int u  = wid * 2 + j;                                             \
      const int rb = (u >> 3) * 128 + (u & 7) * 8 + (h) * 64;                 \
      __builtin_amdgcn_global_load_lds(                                       \
          (const __attribute__((address_space(1))) unsigned int*)(            \
              gA + (size_t)rb * 512 + (size_t)((g) & 3) * 128),               \
          (__attribute__((address_space(3))) unsigned int*)(                  \
              As + ((g) & 1) * 32768 + rb * 128),                             \
          16, 0, 0);                                                          \
    }                                                                         \
  }
#define STAGE_B(g, h)                                                         \
  {                                                                           \
    _Pragma("unroll") for (int j = 0; j < 2; ++j) {                           \
      const int u  = wid * 2 + j;                                             \
      const int rb = (u >> 2) * 64 + (u & 3) * 8 + (h) * 32;                  \
      __builtin_amdgcn_global_load_lds(                                       \
          (const __attribute__((address_space(1))) unsigned int*)(            \
              gB + (size_t)rb * 512 + (size_t)((g) & 3) * 128),               \
          (__attribute__((address_space(3))) unsigned int*)(                  \
              Bs + ((g) & 1) * 32768 + rb * 128),                             \
          16, 0, 0);                                                          \
    }                                                                         \
  }

#define FRAG(base, ro, DSTV)                                                  \
  {                                                                           \
    int4v lo = *reinterpret_cast<const int4v*>((base) + (ro) + c0);           \
    int4v hi = *reinterpret_cast<const int4v*>((base) + (ro) + c1);           \
    DSTV = (int8v){lo[0], lo[1], lo[2], lo[3], hi[0], hi[1], hi[2], hi[3]};   \
  }
#define READ_A(buf, mp, DST)                                                  \
  {                                                                           \
    _Pragma("unroll") for (int mf = 0; mf < 4; ++mf) {                        \
      const int ro = (wr * 128 + (mp)*64 + mf * 16 + r) * 128;                \
      FRAG(As + (buf)*32768, ro, DST[mf]);                                    \
    }                                                                         \
  }
#define READ_B(buf, nh, DST)                                                  \
  {                                                                           \
    _Pragma("unroll") for (int nf = 0; nf < 2; ++nf) {                        \
      const int ro = (wc * 64 + (nh)*32 + nf * 16 + r) * 128;                 \
      FRAG(Bs + (buf)*32768, ro, DST[nf]);                                    \
    }                                                                         \
  }

#define WAITBAR()                                                             \
  asm volatile("s_waitcnt vmcnt(4)\n\ts_barrier" ::: "memory")
#define NOWAITBAR() asm volatile("s_barrier" ::: "memory")

  // 8 MFMA of 16x16x128 fp8 (MX-scaled, scale = 1.0)
#define CLUSTER(mp, nh, AV, BV)                                               \
  {                                                                           \
    __builtin_amdgcn_s_setprio(1);                                            \
    _Pragma("unroll") for (int mf = 0; mf < 4; ++mf)                          \
    _Pragma("unroll") for (int nf = 0; nf < 2; ++nf)                          \
      acc[(mp)*4 + mf][(nh)*2 + nf] =                                         \
          __builtin_amdgcn_mfma_scale_f32_16x16x128_f8f6f4(                   \
              AV[mf], BV[nf], acc[(mp)*4 + mf][(nh)*2 + nf], 0, 0,            \
              0, SCALE1, 0, SCALE1);                                          \
    __builtin_amdgcn_s_setprio(0);                                            \
  }

  // ---- prologue: K-tile 0 into buf0 (8 loads) ----
  STAGE_A(0, 0);
  STAGE_B(0, 0);
  STAGE_A(0, 1);
  STAGE_B(0, 1);
  WAITBAR();  // retires A0h0,B0h0 -> ph1 reads safe

  // ---- main loop: 2 iters x {K-tile e in buf0, e+1 in buf1} ----
  // vmcnt(4) ledger (FIFO-verified): each half-tile retires exactly one
  // barrier before its first ds_read; it=1 ph5-8 stage wrapped K-tile 0
  // into buf0 (wasted but keeps the ledger uniform; no WAR race).
#pragma unroll
  for (int it = 0; it < 2; ++it) {
    const int e = 2 * it;
    // ph1: (m0,n0) of K-tile e
    READ_A(0, 0, aLo);
    READ_B(0, 0, bv0);
    STAGE_A(e + 1, 0);
    WAITBAR();          // retires A-sh1(buf0) -> read ph2
    CLUSTER(0, 0, aLo, bv0);
    // ph2: (m1,n0)
    READ_A(0, 1, aHi);
    STAGE_B(e + 1, 0);
    WAITBAR();          // retires B-sh1(buf0) -> read ph3
    CLUSTER(1, 0, aHi, bv0);
    // ph3: (m0,n1)
    READ_B(0, 1, bv1);
    STAGE_A(e + 1, 1);
    NOWAITBAR();
    CLUSTER(0, 1, aLo, bv1);
    // ph4: (m1,n1)
    STAGE_B(e + 1, 1);
    WAITBAR();          // retires A-sh0,B-sh0(buf1) -> read ph5
    CLUSTER(1, 1, aHi, bv1);
    // ph5: (m0,n0) of K-tile e+1
    READ_A(1, 0, aLo);
    READ_B(1, 0, bv0);
    STAGE_A(e + 2, 0);
    WAITBAR();          // retires A-sh1(buf1) -> read ph6
    CLUSTER(0, 0, aLo, bv0);
    // ph6: (m1,n0)
    READ_A(1, 1, aHi);
    STAGE_B(e + 2, 0);
    WAITBAR();          // retires B-sh1(buf1) -> read ph7
    CLUSTER(1, 0, aHi, bv0);
    // ph7: (m0,n1)
    READ_B(1, 1, bv1);
    STAGE_A(e + 2, 1);
    NOWAITBAR();
    CLUSTER(0, 1, aLo, bv1);
    // ph8: (m1,n1)
    STAGE_B(e + 2, 1);
    WAITBAR();          // retires A-sh0,B-sh0(next buf0) -> next ph1
    CLUSTER(1, 1, aHi, bv1);
  }
  asm volatile("s_waitcnt vmcnt(0)" ::: "memory");  // retire tail stages
#undef STAGE_A
#undef STAGE_B
#undef FRAG
#undef READ_A
#undef READ_B
#undef CLUSTER

  // ---- epilogue: uni = logsig(-s*INV_T); reduce this wave's 64 cols ----
  float part[32];
#pragma unroll
  for (int am = 0; am < 8; ++am)
#pragma unroll
    for (int rr = 0; rr < 4; ++rr) {
      float ssum = 0.0f;
#pragma unroll
      for (int an = 0; an < 4; ++an) {
        float s = acc[am][an][rr] * INV_T;
        ssum += logsig_neg(s);
      }
      part[am * 4 + rr] = ssum;
    }
#pragma unroll
  for (int i = 0; i < 32; ++i) {
    float v = part[i];
    v += __shfl_xor(v, 1);
    v += __shfl_xor(v, 2);
    v += __shfl_xor(v, 4);
    v += __shfl_xor(v, 8);
    part[i] = v;
  }
  if ((lane & 15) == 0) {
    const int gq = lane >> 4;  // row quad within fragment
#pragma unroll
    for (int am = 0; am < 8; ++am)
#pragma unroll
      for (int rr = 0; rr < 4; ++rr)
        atomicAdd(&rowsum[brow + wr * 128 + am * 16 + gq * 4 + rr],
                  part[am * 4 + rr]);
  }
}

__global__ __launch_bounds__(256) void nce_combine(
    const float* __restrict__ ref, const float* __restrict__ pos,
    const float* __restrict__ rowsum, float* __restrict__ out) {
  const int wid  = threadIdx.x >> 6;
  const int lane = threadIdx.x & 63;
  const int n    = blockIdx.x * 4 + wid;

  const f32x4* pr =
      reinterpret_cast<const f32x4*>(ref + (size_t)n * D_ + lane * 8);
  const f32x4* pp =
      reinterpret_cast<const f32x4*>(pos + (size_t)n * D_ + lane * 8);
  f32x4 a0 = pr[0], a1 = pr[1], b0 = pp[0], b1 = pp[1];
  float d = 0.0f;
#pragma unroll
  for (int i = 0; i < 4; ++i) d = __builtin_fmaf(a0[i], b0[i], d);
#pragma unroll
  for (int i = 0; i < 4; ++i) d = __builtin_fmaf(a1[i], b1[i], d);
#pragma unroll
  for (int s = 1; s < 64; s <<= 1) d += __shfl_xor(d, s);

  if (lane == 0) {
    float z = d * INV_T;
    float align   = logsig_neg(-z);
    float uniform = rowsum[n] * (1.0f / (float)M_);
    out[n]          = align + NEG_W * uniform;
    out[N_ + n]     = align;
    out[2 * N_ + n] = uniform;
  }
}

extern "C" void kernel_launch(void* const* d_in, const int* in_sizes, int n_in,
                              void* d_out, int out_size, void* d_ws,
                              size_t ws_size, hipStream_t stream) {
  const float* ref = (const float*)d_in[0];
  const float* pos = (const float*)d_in[1];
  const float* neg = (const float*)d_in[2];
  float* out = (float*)d_out;

  float* rowsum = (float*)d_ws;                                   // 32 KB
  unsigned char* a8 = (unsigned char*)d_ws + 32768;               // 4 MB
  unsigned char* b8 = a8 + (size_t)N_ * D_;                       // 4 MB

  (void)hipFuncSetAttribute((const void*)nce_gemm,
                            hipFuncAttributeMaxDynamicSharedMemorySize,
                            131072);

  hipMemsetAsync(rowsum, 0, N_ * sizeof(float), stream);
  cvt_pack<<<2048, 256, 0, stream>>>(ref, neg, a8, b8);
  nce_gemm<<<1024, 512, 131072, stream>>>(a8, b8, rowsum);
  nce_combine<<<N_ / 4, 256, 0, stream>>>(ref, pos, rowsum, out);
}